// Round 6
// baseline (601.380 us; speedup 1.0000x reference)
//
#include <hip/hip_runtime.h>
#include <hip/hip_bf16.h>
#include <math.h>

#define BATCH 8
#define SEQ   2048
#define DIM   512
#define NH    8
#define DHEAD 64
#define FFD   2048
#define TOPQ  39            // ceil(5*ln(2048)) with factor=5, min_k=5 (fixed harness inputs)
#define MROWS (BATCH*SEQ)   // 16384
#define KC    128           // keys per attention partial block
#define NKC   (SEQ/KC)      // 16
#define PSTR  66            // partial stride: 64 ctx + m + l

typedef __hip_bfloat16 bf16;
typedef __attribute__((ext_vector_type(8))) short short8;
typedef __attribute__((ext_vector_type(4))) float floatx4;

__device__ __forceinline__ float bf2f(short u){
    return __uint_as_float(((unsigned int)(unsigned short)u) << 16);
}
// RNE fp32->bf16 bits (matches hardware convert for finite values)
__device__ __forceinline__ unsigned int f2bf_bits(float f){
    unsigned int u = __float_as_uint(f);
    return (u + 0x7fffu + ((u >> 16) & 1u)) >> 16;
}
// fast gelu (tanh form): |err vs exact erf-gelu| < ~3e-3, << bf16 rounding here
__device__ __forceinline__ float gelu_f(float v){
    float u = v*(0.7978845608028654f + 0.0356774081363f*v*v);
    float e = __expf(2.f*u);
    return 0.5f*v*(2.f - 2.f/(e + 1.f));
}
__device__ __forceinline__ float wave_sum(float v){
    #pragma unroll
    for (int off = 32; off > 0; off >>= 1) v += __shfl_down(v, off);
    return v;
}
__device__ __forceinline__ double wave_sum_d(double v){
    #pragma unroll
    for (int off = 32; off > 0; off >>= 1) v += __shfl_down(v, off);
    return v;
}
// block = 256 threads (4 waves)
__device__ __forceinline__ float block_sum256(float v, float* sbuf){
    v = wave_sum(v);
    if ((threadIdx.x & 63) == 0) sbuf[threadIdx.x >> 6] = v;
    __syncthreads();
    float r = sbuf[0] + sbuf[1] + sbuf[2] + sbuf[3];
    __syncthreads();
    return r;
}
__device__ __forceinline__ double block_sum256d(double v, double* sbuf){
    v = wave_sum_d(v);
    if ((threadIdx.x & 63) == 0) sbuf[threadIdx.x >> 6] = v;
    __syncthreads();
    double r = sbuf[0] + sbuf[1] + sbuf[2] + sbuf[3];
    __syncthreads();
    return r;
}

// async global->LDS, 16 B per lane; LDS dest = wave-uniform base + lane*16
__device__ __forceinline__ void load_lds16(const void* g, void* l){
    auto gp = reinterpret_cast<const uint32_t __attribute__((address_space(1)))*>(
        reinterpret_cast<uintptr_t>(g));
    auto lp = reinterpret_cast<uint32_t __attribute__((address_space(3)))*>(
        reinterpret_cast<uintptr_t>(l));
    __builtin_amdgcn_global_load_lds(gp, lp, 16, 0, 0);
}

__device__ __forceinline__ void store_out(bf16* p, float v){ *p = __float2bfloat16(v); }
__device__ __forceinline__ void store_out(float* p, float v){ *p = v; }

// ---------------------------------------------------------------------------
// 128x128-tile GEMM (m97 structure): C = A(MxK)·B(NxK)^T + bias.
// BK=32, global_load_lds width-16 staging, XOR-swizzled LDS k-octet slots.
// EPI: 1 = gelu->bf16, 2 = +x2 -> fp32 (direct stores: fp32 rows are full
// 64B sectors), 3 = KV head-major scatter (C=Khm, Vhm).
// EPI 1/3 route through an LDS-staged epilogue: col-pair packing via
// shfl_xor(1), per-wave 64x64 bf16 tile at stride 72 (write banks 2-way,
// read banks 2-way = free), then 8 rows x 128 B contiguous per store instr
// -> no partial-sector write amplification.
// ---------------------------------------------------------------------------
template<int EPI, typename OUT_T>
__global__ __launch_bounds__(256) void gemm128_kernel(const bf16* __restrict__ A,
                                                      const bf16* __restrict__ Bm,
                                                      const float* __restrict__ bias,
                                                      OUT_T* __restrict__ C,
                                                      const float* __restrict__ x2,
                                                      bf16* __restrict__ Vhm,
                                                      int K, int ldc)
{
    __shared__ __align__(16) short As[128*32];   // 8 KB
    __shared__ __align__(16) short Bs[128*32];
    constexpr int CS_ELEMS = (EPI == 2) ? 1 : 4*64*72;
    __shared__ __align__(16) short Cs[CS_ELEMS]; // 36 KB for bf16-out epilogue
    const int t    = threadIdx.x;
    const int lane = t & 63;
    const int w    = t >> 6;
    const int lf   = lane & 15;
    const int ko   = lane >> 4;
    const int slot = ko ^ ((lf >> 1) & 3);
    const int mrow = (w >> 1)*64, ncol = (w & 1)*64;

    floatx4 acc[4][4];
    floatx4 z = {0.f,0.f,0.f,0.f};
    #pragma unroll
    for (int i = 0; i < 4; ++i)
        #pragma unroll
        for (int j = 0; j < 4; ++j) acc[i][j] = z;

    // staging: issue j covers tile rows [64j,64j+64); thread -> (row, quad-slot)
    const int srow = w*16 + (lane >> 2);
    const int sq   = lane & 3;
    const int r0 = srow,      kq0 = sq ^ ((r0 >> 1) & 3);
    const int r1 = 64 + srow, kq1 = sq ^ ((r1 >> 1) & 3);
    const short* ga0 = (const short*)A  + ((size_t)blockIdx.y*128 + r0)*K + kq0*8;
    const short* ga1 = (const short*)A  + ((size_t)blockIdx.y*128 + r1)*K + kq1*8;
    const short* gb0 = (const short*)Bm + ((size_t)blockIdx.x*128 + r0)*K + kq0*8;
    const short* gb1 = (const short*)Bm + ((size_t)blockIdx.x*128 + r1)*K + kq1*8;
    char* la0 = (char*)As + w*1024;
    char* la1 = (char*)As + 4096 + w*1024;
    char* lb0 = (char*)Bs + w*1024;
    char* lb1 = (char*)Bs + 4096 + w*1024;

    for (int k0 = 0; k0 < K; k0 += 32){
        load_lds16(ga0, la0); load_lds16(ga1, la1);
        load_lds16(gb0, lb0); load_lds16(gb1, lb1);
        ga0 += 32; ga1 += 32; gb0 += 32; gb1 += 32;
        __syncthreads();                                // compiler drains vmcnt here
        short8 af[4], bfr[4];
        #pragma unroll
        for (int i = 0; i < 4; ++i){
            af[i]  = *(const short8*)(As + (mrow + i*16 + lf)*32 + slot*8);
            bfr[i] = *(const short8*)(Bs + (ncol + i*16 + lf)*32 + slot*8);
        }
        #pragma unroll
        for (int i = 0; i < 4; ++i)
            #pragma unroll
            for (int j = 0; j < 4; ++j)
                acc[i][j] = __builtin_amdgcn_mfma_f32_16x16x32_bf16(af[i], bfr[j], acc[i][j], 0, 0, 0);
        __syncthreads();
    }
    // epilogue: C/D map col = lf, row = ko*4 + r within each 16x16 tile
    if constexpr (EPI == 2){
        const int lr = ko*4;
        #pragma unroll
        for (int j = 0; j < 4; ++j){
            int gcol = blockIdx.x*128 + ncol + j*16 + lf;
            float bv = bias[gcol];
            #pragma unroll
            for (int i = 0; i < 4; ++i){
                #pragma unroll
                for (int r = 0; r < 4; ++r){
                    size_t grow = (size_t)blockIdx.y*128 + mrow + i*16 + lr + r;
                    float v = acc[i][j][r] + bv + x2[grow*ldc + gcol];
                    store_out(&C[grow*ldc + gcol], v);
                }
            }
        }
    } else {
        // stage wave's 64x64 bf16 tile: pack col pairs via shfl_xor(1)
        short* cs = Cs + w*(64*72);
        const int odd = lf & 1;
        const int rsel = odd*2;
        #pragma unroll
        for (int j = 0; j < 4; ++j){
            float bv = bias[blockIdx.x*128 + ncol + j*16 + lf];
            #pragma unroll
            for (int i = 0; i < 4; ++i){
                unsigned long long self = 0;
                #pragma unroll
                for (int r = 0; r < 4; ++r){
                    float v = acc[i][j][r] + bv;
                    if constexpr (EPI == 1) v = gelu_f(v);
                    self |= ((unsigned long long)f2bf_bits(v)) << (16*r);
                }
                unsigned long long nbr = __shfl_xor(self, 1);
                unsigned long long lo = odd ? nbr : self;
                unsigned long long hi = odd ? self : nbr;
                int colb = 16*j + (lf & ~1);
                unsigned int w0 = (unsigned int)((lo >> (16*rsel)) & 0xffffu)
                                | ((unsigned int)((hi >> (16*rsel)) & 0xffffu) << 16);
                unsigned int w1 = (unsigned int)((lo >> (16*(rsel+1))) & 0xffffu)
                                | ((unsigned int)((hi >> (16*(rsel+1))) & 0xffffu) << 16);
                *(unsigned int*)(cs + (16*i + 4*ko + rsel    )*72 + colb) = w0;
                *(unsigned int*)(cs + (16*i + 4*ko + rsel + 1)*72 + colb) = w1;
            }
        }
        // same-wave read-back (lgkmcnt dependency only) + coalesced stores:
        // per instr: 8 rows x 128 B contiguous
        const int subrow = lane >> 3, cq = lane & 7;
        #pragma unroll
        for (int rr = 0; rr < 8; ++rr){
            int rl = rr*8 + subrow;
            short8 vv = *(const short8*)(cs + rl*72 + cq*8);
            if constexpr (EPI == 3){
                int grow = blockIdx.y*128 + mrow + rl;        // b*SEQ + s
                int b = grow >> 11, s = grow & 2047;
                int gc = blockIdx.x*128 + ncol + cq*8;
                int h = (gc >> 6) & 7, d = gc & 63;
                bf16* dst = (gc < 512) ? (bf16*)C : Vhm;
                *(short8*)((short*)dst + (((size_t)(b*NH + h))*SEQ + s)*DHEAD + d) = vv;
            } else {
                size_t grow = (size_t)blockIdx.y*128 + mrow + rl;
                int gcol = blockIdx.x*128 + ncol + cq*8;
                *(short8*)((short*)C + grow*ldc + gcol) = vv;
            }
        }
    }
}

// ---------------------------------------------------------------------------
__global__ void init_kernel(int* selmap){
    int i = blockIdx.x*256 + threadIdx.x;
    if (i < MROWS) selmap[i] = -1;
}

// fp32 -> bf16 weight convert (n multiple of 4)
__global__ __launch_bounds__(256) void cvt_kernel(const float* __restrict__ src,
                                                  bf16* __restrict__ dst, int n){
    int i = (blockIdx.x*256 + threadIdx.x)*4;
    if (i < n){
        float4 v = *(const float4*)(src + i);
        dst[i+0] = __float2bfloat16(v.x);
        dst[i+1] = __float2bfloat16(v.y);
        dst[i+2] = __float2bfloat16(v.z);
        dst[i+3] = __float2bfloat16(v.w);
    }
}

// ---------------------------------------------------------------------------
// LN1 (fp32 in): x -> xn (f32), xnb (bf16), diag[row]=|xn|^2 in fp64 (ranking)
// ---------------------------------------------------------------------------
__global__ __launch_bounds__(256) void ln1_kernel(const float* __restrict__ x,
                                                  const float* __restrict__ g,
                                                  const float* __restrict__ bt,
                                                  float* __restrict__ xn,
                                                  bf16* __restrict__ xnb,
                                                  double* __restrict__ diag)
{
    __shared__ double sbuf[4];
    int row = blockIdx.x;
    int t = threadIdx.x;
    size_t base = (size_t)row*DIM;
    double x0 = (double)x[base + t];
    double x1 = (double)x[base + t + 256];
    double m  = block_sum256d(x0 + x1, sbuf) * (1.0/DIM);
    double d0 = x0 - m, d1 = x1 - m;
    double var = block_sum256d(d0*d0 + d1*d1, sbuf) * (1.0/DIM);
    double r = 1.0/sqrt(var + 1e-5);
    double y0 = d0*r*(double)g[t]     + (double)bt[t];
    double y1 = d1*r*(double)g[t+256] + (double)bt[t+256];
    xn[base+t] = (float)y0;       xn[base+t+256] = (float)y1;
    xnb[base+t] = __float2bfloat16((float)y0);
    xnb[base+t+256] = __float2bfloat16((float)y1);
    double dd = block_sum256d(y0*y0 + y1*y1, sbuf);
    if (t == 0) diag[row] = dd;
}

// column-mean of xn per batch, fp64 two-stage
__global__ __launch_bounds__(512) void xbar_part_kernel(const float* __restrict__ xn, double* __restrict__ part){
    int b = blockIdx.y, c = blockIdx.x, d = threadIdx.x;
    const float* p = xn + ((size_t)b*SEQ + c*64)*DIM + d;
    double s = 0.0;
    for (int i = 0; i < 64; ++i) s += (double)p[(size_t)i*DIM];
    part[((size_t)(b*32 + c))*DIM + d] = s;
}
__global__ __launch_bounds__(512) void xbar_fin_kernel(const double* __restrict__ part,
                                                       double* __restrict__ xbar_d,
                                                       float* __restrict__ xbar_f){
    int b = blockIdx.x, d = threadIdx.x;
    double s = 0.0;
    for (int c = 0; c < 32; ++c) s += part[((size_t)(b*32 + c))*DIM + d];
    s *= (1.0/SEQ);
    xbar_d[(size_t)b*DIM + d] = s;
    xbar_f[(size_t)b*DIM + d] = (float)s;
}

// sparsity*sqrt(D) = diag - dot(xn_row, xbar); fp64 so ranking error << ref fp32 noise
__global__ __launch_bounds__(256) void sparsity_kernel(const float* __restrict__ xn,
                                                       const double* __restrict__ xbar,
                                                       const double* __restrict__ diag,
                                                       double* __restrict__ sp)
{
    int row  = blockIdx.x*4 + (threadIdx.x >> 6);
    int lane = threadIdx.x & 63;
    int b    = row >> 11;
    const float* xr = xn + (size_t)row*DIM;
    const double* xb = xbar + (size_t)b*DIM;
    double s = 0.0;
    for (int e = lane; e < DIM; e += 64) s += (double)xr[e]*xb[e];
    s = wave_sum_d(s);
    if (lane == 0) sp[row] = diag[row] - s;
}

// top-39 per batch (iterative argmax; ties -> lowest index, matching jax top_k)
__global__ __launch_bounds__(256) void topk_kernel(const double* __restrict__ sp,
                                                   int* __restrict__ topidx,
                                                   int* __restrict__ selmap,
                                                   float* __restrict__ dout)
{
    __shared__ double vals[SEQ];
    __shared__ double rv[256];
    __shared__ int    ri[256];
    int b = blockIdx.x, t = threadIdx.x;
    for (int i = t; i < SEQ; i += 256) vals[i] = sp[(size_t)b*SEQ + i];
    __syncthreads();
    for (int it = 0; it < TOPQ; ++it){
        double bv = -1.0e300; int bi = 0;
        for (int i = t; i < SEQ; i += 256){
            double v = vals[i];
            if (v > bv){ bv = v; bi = i; }
        }
        rv[t] = bv; ri[t] = bi;
        __syncthreads();
        for (int stride = 128; stride > 0; stride >>= 1){
            if (t < stride){
                double ov = rv[t+stride]; int oi = ri[t+stride];
                if (ov > rv[t] || (ov == rv[t] && oi < ri[t])){ rv[t] = ov; ri[t] = oi; }
            }
            __syncthreads();
        }
        if (t == 0){
            int idx = ri[0];
            topidx[b*64 + it] = idx;
            selmap[(size_t)b*SEQ + idx] = it;
            vals[idx] = -1.0e300;
        }
        __syncthreads();
    }
    if (b == 0 && t == 0) dout[(size_t)MROWS*DIM] = (float)TOPQ/(float)SEQ;
}

// Q projection for the 39 selected rows (all fp32)
__global__ __launch_bounds__(256) void qproj_kernel(const float* __restrict__ xn,
                                                    const float* __restrict__ in_w,
                                                    const float* __restrict__ in_b,
                                                    const int* __restrict__ topidx,
                                                    float* __restrict__ qrows)
{
    int j = blockIdx.x, b = blockIdx.y, t = threadIdx.x;
    __shared__ float qr[DIM];
    int srow = topidx[b*64 + j];
    const float* xr = xn + ((size_t)(b*SEQ + srow))*DIM;
    for (int i = t; i < DIM; i += 256) qr[i] = xr[i];
    __syncthreads();
    for (int d0 = t; d0 < DIM; d0 += 256){
        const float* wr = in_w + (size_t)d0*DIM;   // Wq row d0
        float s = 0.f;
        for (int e = 0; e < DIM; e += 4){
            float4 wv = *(const float4*)(wr + e);
            s += qr[e]*wv.x + qr[e+1]*wv.y + qr[e+2]*wv.z + qr[e+3]*wv.w;
        }
        qrows[((size_t)(b*TOPQ + j))*DIM + d0] = s + in_b[d0];
    }
}

// ---------------------------------------------------------------------------
// split-K attention pass 1: block = (k-chunk, head, batch) = 1024 blocks.
// ---------------------------------------------------------------------------
__global__ __launch_bounds__(256) void attn_part_kernel(const float* __restrict__ qrows,
                                                        const bf16* __restrict__ Khm,
                                                        const bf16* __restrict__ Vhm,
                                                        float* __restrict__ part)
{
    __shared__ float qh[TOPQ*DHEAD];     // 9984 B
    __shared__ short Vs[KC*DHEAD];       // 16384 B
    __shared__ float sc[TOPQ*KC];        // 19968 B
    int kc = blockIdx.x, h = blockIdx.y, b = blockIdx.z;
    int t = threadIdx.x;
    int w = t >> 6, lane = t & 63;
    for (int i = t; i < TOPQ*DHEAD; i += 256){
        int q = i >> 6, d = i & 63;
        qh[i] = qrows[((size_t)(b*TOPQ + q))*DIM + h*DHEAD + d];
    }
    const short* vg = (const short*)Vhm + ((size_t)((b*NH + h))*SEQ + kc*KC)*DHEAD;
    for (int i = t*8; i < KC*DHEAD; i += 256*8)
        *(uint4*)(Vs + i) = *(const uint4*)(vg + i);
    int kl = (w & 1)*64 + lane;          // 0..127
    int qset = w >> 1;                   // 0 or 1
    const short* kg = (const short*)Khm + ((size_t)((b*NH + h))*SEQ + kc*KC + kl)*DHEAD;
    short8 kr[8];
    #pragma unroll
    for (int e = 0; e < 8; ++e) kr[e] = *(const short8*)(kg + e*8);
    __syncthreads();
    for (int q = qset; q < TOPQ; q += 2){
        float s = 0.f;
        #pragma unroll
        for (int e = 0; e < 8; ++e){
            #pragma unroll
            for (int u = 0; u < 8; ++u) s += qh[q*64 + e*8 + u]*bf2f(kr[e][u]);
        }
        sc[q*KC + kl] = s * 0.125f;      // 1/sqrt(64)
    }
    __syncthreads();
    for (int q = w; q < TOPQ; q += 4){
        float s0 = sc[q*KC + lane], s1 = sc[q*KC + lane + 64];
        float m = fmaxf(s0, s1);
        #pragma unroll
        for (int off = 32; off > 0; off >>= 1) m = fmaxf(m, __shfl_xor(m, off));
        float p0 = __expf(s0 - m), p1 = __expf(s1 - m);
        float l = p0 + p1;
        #pragma unroll
        for (int off = 32; off > 0; off >>= 1) l += __shfl_xor(l, off);
        sc[q*KC + lane] = p0; sc[q*KC + lane + 64] = p1;
        float a = 0.f;
        #pragma unroll 4
        for (int k = 0; k < KC; ++k)
            a += sc[q*KC + k]*bf2f(Vs[k*DHEAD + lane]);
        float* pp = part + ((((size_t)(b*NH + h))*TOPQ + q)*NKC + kc)*PSTR;
        pp[lane] = a;
        if (lane == 0){ pp[64] = m; pp[65] = l; }
    }
}

// pass 2: merge 16 partials per (b,h,q); wave per q (4 q per block)
__global__ __launch_bounds__(256) void attn_reduce_kernel(const float* __restrict__ part,
                                                          float* __restrict__ ctx)
{
    int qc = blockIdx.x, h = blockIdx.y, b = blockIdx.z;
    int w = threadIdx.x >> 6, lane = threadIdx.x & 63;
    int q = qc*4 + w;
    if (q >= TOPQ) return;
    const float* pb = part + (((size_t)(b*NH + h))*TOPQ + q)*NKC*PSTR;
    float M = -3.402823466e38f;
    #pragma unroll
    for (int i = 0; i < NKC; ++i) M = fmaxf(M, pb[i*PSTR + 64]);
    float L = 0.f, a = 0.f;
    #pragma unroll
    for (int i = 0; i < NKC; ++i){
        float sc = __expf(pb[i*PSTR + 64] - M);
        L += pb[i*PSTR + 65]*sc;
        a += pb[i*PSTR + lane]*sc;
    }
    ctx[((size_t)(b*TOPQ + q))*DIM + h*DHEAD + lane] = a/L;
}

// output projection of the 39 ctx rows (fp32 weights)
__global__ __launch_bounds__(256) void outproj_kernel(const float* __restrict__ ctx,
                                                      const float* __restrict__ ow,
                                                      const float* __restrict__ ob,
                                                      float* __restrict__ sout)
{
    int j = blockIdx.x, b = blockIdx.y, t = threadIdx.x;
    __shared__ float cr[DIM];
    const float* xr = ctx + ((size_t)(b*TOPQ + j))*DIM;
    for (int i = t; i < DIM; i += 256) cr[i] = xr[i];
    __syncthreads();
    for (int d0 = t; d0 < DIM; d0 += 256){
        const float* wr = ow + (size_t)d0*DIM;
        float s = 0.f;
        for (int e = 0; e < DIM; e += 4){
            float4 wv = *(const float4*)(wr + e);
            s += cr[e]*wv.x + cr[e+1]*wv.y + cr[e+2]*wv.z + cr[e+3]*wv.w;
        }
        sout[((size_t)(b*TOPQ + j))*DIM + d0] = s + ob[d0];
    }
}

// residual (+ scatter sparse rows / broadcast xbar) then LN2 -> h (bf16), x2 (f32)
__global__ __launch_bounds__(256) void res_ln2_kernel(const float* __restrict__ x,
                                                      const float* __restrict__ xbar,
                                                      const float* __restrict__ sout,
                                                      const int* __restrict__ selmap,
                                                      const float* __restrict__ g2,
                                                      const float* __restrict__ bt2,
                                                      float* __restrict__ x2,
                                                      bf16* __restrict__ hb)
{
    __shared__ float sbuf[4];
    int row = blockIdx.x;
    int b = row >> 11;
    int t = threadIdx.x;
    int slot = selmap[row];
    const float* ar = (slot >= 0) ? (sout + ((size_t)(b*TOPQ + slot))*DIM)
                                  : (xbar + (size_t)b*DIM);
    size_t base = (size_t)row*DIM;
    float v0 = x[base + t]       + ar[t];
    float v1 = x[base + t + 256] + ar[t + 256];
    x2[base + t] = v0; x2[base + t + 256] = v1;
    float m = block_sum256(v0 + v1, sbuf) * (1.f/DIM);
    float d0 = v0 - m, d1 = v1 - m;
    float var = block_sum256(d0*d0 + d1*d1, sbuf) * (1.f/DIM);
    float r = 1.f/sqrtf(var + 1e-5f);
    hb[base + t]       = __float2bfloat16(d0*r*g2[t]     + bt2[t]);
    hb[base + t + 256] = __float2bfloat16(d1*r*g2[t+256] + bt2[t+256]);
}

// ---------------------------------------------------------------------------
extern "C" void kernel_launch(void* const* d_in, const int* in_sizes, int n_in,
                              void* d_out, int out_size, void* d_ws, size_t ws_size,
                              hipStream_t stream)
{
    (void)in_sizes; (void)n_in; (void)out_size; (void)ws_size;
    const float* x     = (const float*)d_in[0];
    const float* ln1_g = (const float*)d_in[1];
    const float* ln1_b = (const float*)d_in[2];
    const float* in_w  = (const float*)d_in[3];
    const float* in_b  = (const float*)d_in[4];
    const float* out_w = (const float*)d_in[5];
    const float* out_b = (const float*)d_in[6];
    const float* ln2_g = (const float*)d_in[7];
    const float* ln2_b = (const float*)d_in[8];
    const float* w1    = (const float*)d_in[9];
    const float* b1    = (const float*)d_in[10];
    const float* w2    = (const float*)d_in[11];
    const float* b2    = (const float*)d_in[12];
    float* out = (float*)d_out;

    const size_t MB = 1024*1024;
    char* base = (char*)d_ws;
    float* xn_f  = (float*)base;                 // [0,32MiB); reused as x2_f later
    bf16*  xn_b  = (bf16*)(base + 32*MB);        // dead after kv-gemm -> h_b
    bf16*  Khm   = (bf16*)(base + 48*MB);
    bf16*  Vhm   = (bf16*)(base + 64*MB);
    bf16*  h_b   = (bf16*)(base + 32*MB);
    bf16*  h1_b  = (bf16*)(base + 48*MB);        // overwrites Khm/Vhm after attn
    float* x2_f  = xn_f;
    char* p = base + 112*MB;
    bf16*  kvw_b  = (bf16*)p;  p += (size_t)1024*DIM*2;        // in_w rows [512,1536) bf16
    bf16*  w1_b   = (bf16*)p;  p += (size_t)FFD*DIM*2;
    bf16*  w2_b   = (bf16*)p;  p += (size_t)DIM*FFD*2;
    double* xbpart= (double*)p; p += (size_t)BATCH*32*DIM*8;
    double* xbar_d= (double*)p; p += (size_t)BATCH*DIM*8;
    float* xbar_f = (float*)p;  p += (size_t)BATCH*DIM*4;
    double* diag  = (double*)p; p += (size_t)MROWS*8;
    double* spars = (double*)p; p += (size_t)MROWS*8;
    int*   topidx = (int*)p;    p += (size_t)BATCH*64*4;
    int*   selmap = (int*)p;    p += (size_t)MROWS*4;
    float* qrows  = (float*)p;  p += (size_t)BATCH*TOPQ*DIM*4;
    float* ctxb   = (float*)p;  p += (size_t)BATCH*TOPQ*DIM*4;
    float* sout   = (float*)p;  p += (size_t)BATCH*TOPQ*DIM*4;
    float* apart  = (float*)p;  p += (size_t)BATCH*NH*TOPQ*NKC*PSTR*4;  // 10.5 MB

    init_kernel<<<64, 256, 0, stream>>>(selmap);
    cvt_kernel<<<512,  256, 0, stream>>>(in_w + (size_t)DIM*DIM, kvw_b, 1024*DIM);
    cvt_kernel<<<1024, 256, 0, stream>>>(w1, w1_b, FFD*DIM);
    cvt_kernel<<<1024, 256, 0, stream>>>(w2, w2_b, DIM*FFD);
    ln1_kernel<<<MROWS, 256, 0, stream>>>(x, ln1_g, ln1_b, xn_f, xn_b, diag);
    xbar_part_kernel<<<dim3(32, BATCH), 512, 0, stream>>>(xn_f, xbpart);
    xbar_fin_kernel<<<BATCH, 512, 0, stream>>>(xbpart, xbar_d, xbar_f);
    sparsity_kernel<<<MROWS/4, 256, 0, stream>>>(xn_f, xbar_d, diag, spars);
    topk_kernel<<<BATCH, 256, 0, stream>>>(spars, topidx, selmap, out);
    // KV projection (N=1024 -> head-major K/V)
    gemm128_kernel<3, bf16><<<dim3(1024/128, MROWS/128), 256, 0, stream>>>(
        xn_b, kvw_b, in_b + DIM, Khm, nullptr, Vhm, DIM, 0);
    qproj_kernel<<<dim3(TOPQ, BATCH), 256, 0, stream>>>(xn_f, in_w, in_b, topidx, qrows);
    attn_part_kernel<<<dim3(NKC, NH, BATCH), 256, 0, stream>>>(qrows, Khm, Vhm, apart);
    attn_reduce_kernel<<<dim3((TOPQ + 3)/4, NH, BATCH), 256, 0, stream>>>(apart, ctxb);
    outproj_kernel<<<dim3(TOPQ, BATCH), 256, 0, stream>>>(ctxb, out_w, out_b, sout);
    res_ln2_kernel<<<MROWS, 256, 0, stream>>>(x, xbar_f, sout, selmap, ln2_g, ln2_b, x2_f, h_b);
    gemm128_kernel<1, bf16><<<dim3(FFD/128, MROWS/128), 256, 0, stream>>>(
        h_b, w1_b, b1, h1_b, nullptr, nullptr, DIM, FFD);
    gemm128_kernel<2, float><<<dim3(DIM/128, MROWS/128), 256, 0, stream>>>(
        h1_b, w2_b, b2, out, x2_f, nullptr, FFD, DIM);
}

// Round 7
// 570.987 us; speedup vs baseline: 1.0532x; 1.0532x over previous
//
#include <hip/hip_runtime.h>
#include <hip/hip_bf16.h>
#include <math.h>

#define BATCH 8
#define SEQ   2048
#define DIM   512
#define NH    8
#define DHEAD 64
#define FFD   2048
#define TOPQ  39            // ceil(5*ln(2048)) with factor=5, min_k=5 (fixed harness inputs)
#define MROWS (BATCH*SEQ)   // 16384
#define KC    128           // keys per attention partial block
#define NKC   (SEQ/KC)      // 16
#define PSTR  66            // partial stride: 64 ctx + m + l

typedef __hip_bfloat16 bf16;
typedef __attribute__((ext_vector_type(8))) short short8;
typedef __attribute__((ext_vector_type(4))) float floatx4;

__device__ __forceinline__ float bf2f(short u){
    return __uint_as_float(((unsigned int)(unsigned short)u) << 16);
}
// RNE fp32->bf16 bits (matches hardware convert for finite values)
__device__ __forceinline__ unsigned int f2bf_bits(float f){
    unsigned int u = __float_as_uint(f);
    return (u + 0x7fffu + ((u >> 16) & 1u)) >> 16;
}
// fast gelu (tanh form): |err vs exact erf-gelu| < ~3e-3, << bf16 rounding here
__device__ __forceinline__ float gelu_f(float v){
    float u = v*(0.7978845608028654f + 0.0356774081363f*v*v);
    float e = __expf(2.f*u);
    return 0.5f*v*(2.f - 2.f/(e + 1.f));
}
__device__ __forceinline__ float wave_sum(float v){
    #pragma unroll
    for (int off = 32; off > 0; off >>= 1) v += __shfl_down(v, off);
    return v;
}
__device__ __forceinline__ double wave_sum_d(double v){
    #pragma unroll
    for (int off = 32; off > 0; off >>= 1) v += __shfl_down(v, off);
    return v;
}
// block = 256 threads (4 waves)
__device__ __forceinline__ float block_sum256(float v, float* sbuf){
    v = wave_sum(v);
    if ((threadIdx.x & 63) == 0) sbuf[threadIdx.x >> 6] = v;
    __syncthreads();
    float r = sbuf[0] + sbuf[1] + sbuf[2] + sbuf[3];
    __syncthreads();
    return r;
}
__device__ __forceinline__ double block_sum256d(double v, double* sbuf){
    v = wave_sum_d(v);
    if ((threadIdx.x & 63) == 0) sbuf[threadIdx.x >> 6] = v;
    __syncthreads();
    double r = sbuf[0] + sbuf[1] + sbuf[2] + sbuf[3];
    __syncthreads();
    return r;
}

// async global->LDS, 16 B per lane; LDS dest = wave-uniform base + lane*16
__device__ __forceinline__ void load_lds16(const void* g, void* l){
    auto gp = reinterpret_cast<const uint32_t __attribute__((address_space(1)))*>(
        reinterpret_cast<uintptr_t>(g));
    auto lp = reinterpret_cast<uint32_t __attribute__((address_space(3)))*>(
        reinterpret_cast<uintptr_t>(l));
    __builtin_amdgcn_global_load_lds(gp, lp, 16, 0, 0);
}

__device__ __forceinline__ void store_out(bf16* p, float v){ *p = __float2bfloat16(v); }
__device__ __forceinline__ void store_out(float* p, float v){ *p = v; }

// ---------------------------------------------------------------------------
// 128x128-tile GEMM (m97 structure): C = A(MxK)·B(NxK)^T + bias.
// BK=32, global_load_lds width-16 staging, XOR-swizzled LDS k-octet slots.
// Round-7 changes:
//  * LDS union: Cs (36 KB epilogue stage) overlaps As/Bs (dead after the
//    K-loop's final barrier) -> LDS block 36.8 KB (EPI 1/3) / 16.4 KB (EPI 2)
//    -> 4 blocks/CU, so per-block vmcnt(0) barrier drains overlap across
//    independent blocks (m114).
//  * XCD-aware 1-D grid swizzle: lid=(bid&7)*per+(bid>>3), x-fastest decode
//    -> each XCD owns a contiguous y-stripe; its A-slice + full B fit its
//    4 MB L2 -> kills the 4x A re-fetch seen at FETCH_SIZE.
// EPI: 1 = gelu->bf16, 2 = +x2 -> fp32 (direct stores), 3 = KV head-major.
// ---------------------------------------------------------------------------
template<int EPI, typename OUT_T>
__global__ __launch_bounds__(256, 4) void gemm128_kernel(const bf16* __restrict__ A,
                                                         const bf16* __restrict__ Bm,
                                                         const float* __restrict__ bias,
                                                         OUT_T* __restrict__ C,
                                                         const float* __restrict__ x2,
                                                         bf16* __restrict__ Vhm,
                                                         int K, int ldc, int lgGX)
{
    constexpr int SMEM = (EPI == 2) ? 16384 : 36864;
    __shared__ __align__(16) char smem[SMEM];
    short* As = (short*)smem;            // 128x32, live during K-loop
    short* Bs = (short*)(smem + 8192);
    short* CsBase = (short*)smem;        // 4 waves x 64x72, live after K-loop

    // XCD-aware swizzle: contiguous y-stripe per XCD, x fastest within stripe
    const int bid = blockIdx.x;
    const int per = gridDim.x >> 3;
    const int lid = (bid & 7)*per + (bid >> 3);
    const int bx  = lid & ((1 << lgGX) - 1);
    const int by  = lid >> lgGX;

    const int t    = threadIdx.x;
    const int lane = t & 63;
    const int w    = t >> 6;
    const int lf   = lane & 15;
    const int ko   = lane >> 4;
    const int slot = ko ^ ((lf >> 1) & 3);
    const int mrow = (w >> 1)*64, ncol = (w & 1)*64;

    floatx4 acc[4][4];
    floatx4 z = {0.f,0.f,0.f,0.f};
    #pragma unroll
    for (int i = 0; i < 4; ++i)
        #pragma unroll
        for (int j = 0; j < 4; ++j) acc[i][j] = z;

    // staging: issue j covers tile rows [64j,64j+64); thread -> (row, quad-slot)
    const int srow = w*16 + (lane >> 2);
    const int sq   = lane & 3;
    const int r0 = srow,      kq0 = sq ^ ((r0 >> 1) & 3);
    const int r1 = 64 + srow, kq1 = sq ^ ((r1 >> 1) & 3);
    const short* ga0 = (const short*)A  + ((size_t)by*128 + r0)*K + kq0*8;
    const short* ga1 = (const short*)A  + ((size_t)by*128 + r1)*K + kq1*8;
    const short* gb0 = (const short*)Bm + ((size_t)bx*128 + r0)*K + kq0*8;
    const short* gb1 = (const short*)Bm + ((size_t)bx*128 + r1)*K + kq1*8;
    char* la0 = (char*)As + w*1024;
    char* la1 = (char*)As + 4096 + w*1024;
    char* lb0 = (char*)Bs + w*1024;
    char* lb1 = (char*)Bs + 4096 + w*1024;

    for (int k0 = 0; k0 < K; k0 += 32){
        load_lds16(ga0, la0); load_lds16(ga1, la1);
        load_lds16(gb0, lb0); load_lds16(gb1, lb1);
        ga0 += 32; ga1 += 32; gb0 += 32; gb1 += 32;
        __syncthreads();                                // compiler drains vmcnt here
        short8 af[4], bfr[4];
        #pragma unroll
        for (int i = 0; i < 4; ++i){
            af[i]  = *(const short8*)(As + (mrow + i*16 + lf)*32 + slot*8);
            bfr[i] = *(const short8*)(Bs + (ncol + i*16 + lf)*32 + slot*8);
        }
        #pragma unroll
        for (int i = 0; i < 4; ++i)
            #pragma unroll
            for (int j = 0; j < 4; ++j)
                acc[i][j] = __builtin_amdgcn_mfma_f32_16x16x32_bf16(af[i], bfr[j], acc[i][j], 0, 0, 0);
        __syncthreads();                                // after this, As/Bs dead -> Cs may alias
    }
    // epilogue: C/D map col = lf, row = ko*4 + r within each 16x16 tile
    if constexpr (EPI == 2){
        const int lr = ko*4;
        #pragma unroll
        for (int j = 0; j < 4; ++j){
            int gcol = bx*128 + ncol + j*16 + lf;
            float bv = bias[gcol];
            #pragma unroll
            for (int i = 0; i < 4; ++i){
                #pragma unroll
                for (int r = 0; r < 4; ++r){
                    size_t grow = (size_t)by*128 + mrow + i*16 + lr + r;
                    float v = acc[i][j][r] + bv + x2[grow*ldc + gcol];
                    store_out(&C[grow*ldc + gcol], v);
                }
            }
        }
    } else {
        // stage wave's 64x64 bf16 tile in (now-dead) As/Bs space
        short* cs = CsBase + w*(64*72);
        const int odd = lf & 1;
        const int rsel = odd*2;
        #pragma unroll
        for (int j = 0; j < 4; ++j){
            float bv = bias[bx*128 + ncol + j*16 + lf];
            #pragma unroll
            for (int i = 0; i < 4; ++i){
                unsigned long long self = 0;
                #pragma unroll
                for (int r = 0; r < 4; ++r){
                    float v = acc[i][j][r] + bv;
                    if constexpr (EPI == 1) v = gelu_f(v);
                    self |= ((unsigned long long)f2bf_bits(v)) << (16*r);
                }
                unsigned long long nbr = __shfl_xor(self, 1);
                unsigned long long lo = odd ? nbr : self;
                unsigned long long hi = odd ? self : nbr;
                int colb = 16*j + (lf & ~1);
                unsigned int w0 = (unsigned int)((lo >> (16*rsel)) & 0xffffu)
                                | ((unsigned int)((hi >> (16*rsel)) & 0xffffu) << 16);
                unsigned int w1 = (unsigned int)((lo >> (16*(rsel+1))) & 0xffffu)
                                | ((unsigned int)((hi >> (16*(rsel+1))) & 0xffffu) << 16);
                *(unsigned int*)(cs + (16*i + 4*ko + rsel    )*72 + colb) = w0;
                *(unsigned int*)(cs + (16*i + 4*ko + rsel + 1)*72 + colb) = w1;
            }
        }
        // same-wave read-back + coalesced stores: 8 rows x 128 B per instr
        const int subrow = lane >> 3, cq = lane & 7;
        #pragma unroll
        for (int rr = 0; rr < 8; ++rr){
            int rl = rr*8 + subrow;
            short8 vv = *(const short8*)(cs + rl*72 + cq*8);
            if constexpr (EPI == 3){
                int grow = by*128 + mrow + rl;        // b*SEQ + s
                int b = grow >> 11, s = grow & 2047;
                int gc = bx*128 + ncol + cq*8;
                int h = (gc >> 6) & 7, d = gc & 63;
                bf16* dst = (gc < 512) ? (bf16*)C : Vhm;
                *(short8*)((short*)dst + (((size_t)(b*NH + h))*SEQ + s)*DHEAD + d) = vv;
            } else {
                size_t grow = (size_t)by*128 + mrow + rl;
                int gcol = bx*128 + ncol + cq*8;
                *(short8*)((short*)C + grow*ldc + gcol) = vv;
            }
        }
    }
}

// ---------------------------------------------------------------------------
__global__ void init_kernel(int* selmap){
    int i = blockIdx.x*256 + threadIdx.x;
    if (i < MROWS) selmap[i] = -1;
}

// fp32 -> bf16 weight convert (n multiple of 4)
__global__ __launch_bounds__(256) void cvt_kernel(const float* __restrict__ src,
                                                  bf16* __restrict__ dst, int n){
    int i = (blockIdx.x*256 + threadIdx.x)*4;
    if (i < n){
        float4 v = *(const float4*)(src + i);
        dst[i+0] = __float2bfloat16(v.x);
        dst[i+1] = __float2bfloat16(v.y);
        dst[i+2] = __float2bfloat16(v.z);
        dst[i+3] = __float2bfloat16(v.w);
    }
}

// ---------------------------------------------------------------------------
// LN1 (fp32 in): x -> xn (f32), xnb (bf16), diag[row]=|xn|^2 in fp64 (ranking)
// ---------------------------------------------------------------------------
__global__ __launch_bounds__(256) void ln1_kernel(const float* __restrict__ x,
                                                  const float* __restrict__ g,
                                                  const float* __restrict__ bt,
                                                  float* __restrict__ xn,
                                                  bf16* __restrict__ xnb,
                                                  double* __restrict__ diag)
{
    __shared__ double sbuf[4];
    int row = blockIdx.x;
    int t = threadIdx.x;
    size_t base = (size_t)row*DIM;
    double x0 = (double)x[base + t];
    double x1 = (double)x[base + t + 256];
    double m  = block_sum256d(x0 + x1, sbuf) * (1.0/DIM);
    double d0 = x0 - m, d1 = x1 - m;
    double var = block_sum256d(d0*d0 + d1*d1, sbuf) * (1.0/DIM);
    double r = 1.0/sqrt(var + 1e-5);
    double y0 = d0*r*(double)g[t]     + (double)bt[t];
    double y1 = d1*r*(double)g[t+256] + (double)bt[t+256];
    xn[base+t] = (float)y0;       xn[base+t+256] = (float)y1;
    xnb[base+t] = __float2bfloat16((float)y0);
    xnb[base+t+256] = __float2bfloat16((float)y1);
    double dd = block_sum256d(y0*y0 + y1*y1, sbuf);
    if (t == 0) diag[row] = dd;
}

// column-mean of xn per batch, fp64 two-stage
__global__ __launch_bounds__(512) void xbar_part_kernel(const float* __restrict__ xn, double* __restrict__ part){
    int b = blockIdx.y, c = blockIdx.x, d = threadIdx.x;
    const float* p = xn + ((size_t)b*SEQ + c*64)*DIM + d;
    double s = 0.0;
    for (int i = 0; i < 64; ++i) s += (double)p[(size_t)i*DIM];
    part[((size_t)(b*32 + c))*DIM + d] = s;
}
__global__ __launch_bounds__(512) void xbar_fin_kernel(const double* __restrict__ part,
                                                       double* __restrict__ xbar_d,
                                                       float* __restrict__ xbar_f){
    int b = blockIdx.x, d = threadIdx.x;
    double s = 0.0;
    for (int c = 0; c < 32; ++c) s += part[((size_t)(b*32 + c))*DIM + d];
    s *= (1.0/SEQ);
    xbar_d[(size_t)b*DIM + d] = s;
    xbar_f[(size_t)b*DIM + d] = (float)s;
}

// sparsity*sqrt(D) = diag - dot(xn_row, xbar); fp64 so ranking error << ref fp32 noise
__global__ __launch_bounds__(256) void sparsity_kernel(const float* __restrict__ xn,
                                                       const double* __restrict__ xbar,
                                                       const double* __restrict__ diag,
                                                       double* __restrict__ sp)
{
    int row  = blockIdx.x*4 + (threadIdx.x >> 6);
    int lane = threadIdx.x & 63;
    int b    = row >> 11;
    const float* xr = xn + (size_t)row*DIM;
    const double* xb = xbar + (size_t)b*DIM;
    double s = 0.0;
    for (int e = lane; e < DIM; e += 64) s += (double)xr[e]*xb[e];
    s = wave_sum_d(s);
    if (lane == 0) sp[row] = diag[row] - s;
}

// top-39 per batch (iterative argmax; ties -> lowest index, matching jax top_k)
__global__ __launch_bounds__(256) void topk_kernel(const double* __restrict__ sp,
                                                   int* __restrict__ topidx,
                                                   int* __restrict__ selmap,
                                                   float* __restrict__ dout)
{
    __shared__ double vals[SEQ];
    __shared__ double rv[256];
    __shared__ int    ri[256];
    int b = blockIdx.x, t = threadIdx.x;
    for (int i = t; i < SEQ; i += 256) vals[i] = sp[(size_t)b*SEQ + i];
    __syncthreads();
    for (int it = 0; it < TOPQ; ++it){
        double bv = -1.0e300; int bi = 0;
        for (int i = t; i < SEQ; i += 256){
            double v = vals[i];
            if (v > bv){ bv = v; bi = i; }
        }
        rv[t] = bv; ri[t] = bi;
        __syncthreads();
        for (int stride = 128; stride > 0; stride >>= 1){
            if (t < stride){
                double ov = rv[t+stride]; int oi = ri[t+stride];
                if (ov > rv[t] || (ov == rv[t] && oi < ri[t])){ rv[t] = ov; ri[t] = oi; }
            }
            __syncthreads();
        }
        if (t == 0){
            int idx = ri[0];
            topidx[b*64 + it] = idx;
            selmap[(size_t)b*SEQ + idx] = it;
            vals[idx] = -1.0e300;
        }
        __syncthreads();
    }
    if (b == 0 && t == 0) dout[(size_t)MROWS*DIM] = (float)TOPQ/(float)SEQ;
}

// Q projection for the 39 selected rows (all fp32)
__global__ __launch_bounds__(256) void qproj_kernel(const float* __restrict__ xn,
                                                    const float* __restrict__ in_w,
                                                    const float* __restrict__ in_b,
                                                    const int* __restrict__ topidx,
                                                    float* __restrict__ qrows)
{
    int j = blockIdx.x, b = blockIdx.y, t = threadIdx.x;
    __shared__ float qr[DIM];
    int srow = topidx[b*64 + j];
    const float* xr = xn + ((size_t)(b*SEQ + srow))*DIM;
    for (int i = t; i < DIM; i += 256) qr[i] = xr[i];
    __syncthreads();
    for (int d0 = t; d0 < DIM; d0 += 256){
        const float* wr = in_w + (size_t)d0*DIM;   // Wq row d0
        float s = 0.f;
        for (int e = 0; e < DIM; e += 4){
            float4 wv = *(const float4*)(wr + e);
            s += qr[e]*wv.x + qr[e+1]*wv.y + qr[e+2]*wv.z + qr[e+3]*wv.w;
        }
        qrows[((size_t)(b*TOPQ + j))*DIM + d0] = s + in_b[d0];
    }
}

// ---------------------------------------------------------------------------
// split-K attention pass 1: block = (k-chunk, head, batch) = 1024 blocks.
// ---------------------------------------------------------------------------
__global__ __launch_bounds__(256) void attn_part_kernel(const float* __restrict__ qrows,
                                                        const bf16* __restrict__ Khm,
                                                        const bf16* __restrict__ Vhm,
                                                        float* __restrict__ part)
{
    __shared__ float qh[TOPQ*DHEAD];     // 9984 B
    __shared__ short Vs[KC*DHEAD];       // 16384 B
    __shared__ float sc[TOPQ*KC];        // 19968 B
    int kc = blockIdx.x, h = blockIdx.y, b = blockIdx.z;
    int t = threadIdx.x;
    int w = t >> 6, lane = t & 63;
    for (int i = t; i < TOPQ*DHEAD; i += 256){
        int q = i >> 6, d = i & 63;
        qh[i] = qrows[((size_t)(b*TOPQ + q))*DIM + h*DHEAD + d];
    }
    const short* vg = (const short*)Vhm + ((size_t)((b*NH + h))*SEQ + kc*KC)*DHEAD;
    for (int i = t*8; i < KC*DHEAD; i += 256*8)
        *(uint4*)(Vs + i) = *(const uint4*)(vg + i);
    int kl = (w & 1)*64 + lane;          // 0..127
    int qset = w >> 1;                   // 0 or 1
    const short* kg = (const short*)Khm + ((size_t)((b*NH + h))*SEQ + kc*KC + kl)*DHEAD;
    short8 kr[8];
    #pragma unroll
    for (int e = 0; e < 8; ++e) kr[e] = *(const short8*)(kg + e*8);
    __syncthreads();
    for (int q = qset; q < TOPQ; q += 2){
        float s = 0.f;
        #pragma unroll
        for (int e = 0; e < 8; ++e){
            #pragma unroll
            for (int u = 0; u < 8; ++u) s += qh[q*64 + e*8 + u]*bf2f(kr[e][u]);
        }
        sc[q*KC + kl] = s * 0.125f;      // 1/sqrt(64)
    }
    __syncthreads();
    for (int q = w; q < TOPQ; q += 4){
        float s0 = sc[q*KC + lane], s1 = sc[q*KC + lane + 64];
        float m = fmaxf(s0, s1);
        #pragma unroll
        for (int off = 32; off > 0; off >>= 1) m = fmaxf(m, __shfl_xor(m, off));
        float p0 = __expf(s0 - m), p1 = __expf(s1 - m);
        float l = p0 + p1;
        #pragma unroll
        for (int off = 32; off > 0; off >>= 1) l += __shfl_xor(l, off);
        sc[q*KC + lane] = p0; sc[q*KC + lane + 64] = p1;
        float a = 0.f;
        #pragma unroll 4
        for (int k = 0; k < KC; ++k)
            a += sc[q*KC + k]*bf2f(Vs[k*DHEAD + lane]);
        float* pp = part + ((((size_t)(b*NH + h))*TOPQ + q)*NKC + kc)*PSTR;
        pp[lane] = a;
        if (lane == 0){ pp[64] = m; pp[65] = l; }
    }
}

// pass 2: merge 16 partials per (b,h,q); wave per q (4 q per block)
__global__ __launch_bounds__(256) void attn_reduce_kernel(const float* __restrict__ part,
                                                          float* __restrict__ ctx)
{
    int qc = blockIdx.x, h = blockIdx.y, b = blockIdx.z;
    int w = threadIdx.x >> 6, lane = threadIdx.x & 63;
    int q = qc*4 + w;
    if (q >= TOPQ) return;
    const float* pb = part + (((size_t)(b*NH + h))*TOPQ + q)*NKC*PSTR;
    float M = -3.402823466e38f;
    #pragma unroll
    for (int i = 0; i < NKC; ++i) M = fmaxf(M, pb[i*PSTR + 64]);
    float L = 0.f, a = 0.f;
    #pragma unroll
    for (int i = 0; i < NKC; ++i){
        float sc = __expf(pb[i*PSTR + 64] - M);
        L += pb[i*PSTR + 65]*sc;
        a += pb[i*PSTR + lane]*sc;
    }
    ctx[((size_t)(b*TOPQ + q))*DIM + h*DHEAD + lane] = a/L;
}

// output projection of the 39 ctx rows (fp32 weights)
__global__ __launch_bounds__(256) void outproj_kernel(const float* __restrict__ ctx,
                                                      const float* __restrict__ ow,
                                                      const float* __restrict__ ob,
                                                      float* __restrict__ sout)
{
    int j = blockIdx.x, b = blockIdx.y, t = threadIdx.x;
    __shared__ float cr[DIM];
    const float* xr = ctx + ((size_t)(b*TOPQ + j))*DIM;
    for (int i = t; i < DIM; i += 256) cr[i] = xr[i];
    __syncthreads();
    for (int d0 = t; d0 < DIM; d0 += 256){
        const float* wr = ow + (size_t)d0*DIM;
        float s = 0.f;
        for (int e = 0; e < DIM; e += 4){
            float4 wv = *(const float4*)(wr + e);
            s += cr[e]*wv.x + cr[e+1]*wv.y + cr[e+2]*wv.z + cr[e+3]*wv.w;
        }
        sout[((size_t)(b*TOPQ + j))*DIM + d0] = s + ob[d0];
    }
}

// residual (+ scatter sparse rows / broadcast xbar) then LN2 -> h (bf16), x2 (f32)
__global__ __launch_bounds__(256) void res_ln2_kernel(const float* __restrict__ x,
                                                      const float* __restrict__ xbar,
                                                      const float* __restrict__ sout,
                                                      const int* __restrict__ selmap,
                                                      const float* __restrict__ g2,
                                                      const float* __restrict__ bt2,
                                                      float* __restrict__ x2,
                                                      bf16* __restrict__ hb)
{
    __shared__ float sbuf[4];
    int row = blockIdx.x;
    int b = row >> 11;
    int t = threadIdx.x;
    int slot = selmap[row];
    const float* ar = (slot >= 0) ? (sout + ((size_t)(b*TOPQ + slot))*DIM)
                                  : (xbar + (size_t)b*DIM);
    size_t base = (size_t)row*DIM;
    float v0 = x[base + t]       + ar[t];
    float v1 = x[base + t + 256] + ar[t + 256];
    x2[base + t] = v0; x2[base + t + 256] = v1;
    float m = block_sum256(v0 + v1, sbuf) * (1.f/DIM);
    float d0 = v0 - m, d1 = v1 - m;
    float var = block_sum256(d0*d0 + d1*d1, sbuf) * (1.f/DIM);
    float r = 1.f/sqrtf(var + 1e-5f);
    hb[base + t]       = __float2bfloat16(d0*r*g2[t]     + bt2[t]);
    hb[base + t + 256] = __float2bfloat16(d1*r*g2[t+256] + bt2[t+256]);
}

// ---------------------------------------------------------------------------
extern "C" void kernel_launch(void* const* d_in, const int* in_sizes, int n_in,
                              void* d_out, int out_size, void* d_ws, size_t ws_size,
                              hipStream_t stream)
{
    (void)in_sizes; (void)n_in; (void)out_size; (void)ws_size;
    const float* x     = (const float*)d_in[0];
    const float* ln1_g = (const float*)d_in[1];
    const float* ln1_b = (const float*)d_in[2];
    const float* in_w  = (const float*)d_in[3];
    const float* in_b  = (const float*)d_in[4];
    const float* out_w = (const float*)d_in[5];
    const float* out_b = (const float*)d_in[6];
    const float* ln2_g = (const float*)d_in[7];
    const float* ln2_b = (const float*)d_in[8];
    const float* w1    = (const float*)d_in[9];
    const float* b1    = (const float*)d_in[10];
    const float* w2    = (const float*)d_in[11];
    const float* b2    = (const float*)d_in[12];
    float* out = (float*)d_out;

    const size_t MB = 1024*1024;
    char* base = (char*)d_ws;
    float* xn_f  = (float*)base;                 // [0,32MiB); reused as x2_f later
    bf16*  xn_b  = (bf16*)(base + 32*MB);        // dead after kv-gemm -> h_b
    bf16*  Khm   = (bf16*)(base + 48*MB);
    bf16*  Vhm   = (bf16*)(base + 64*MB);
    bf16*  h_b   = (bf16*)(base + 32*MB);
    bf16*  h1_b  = (bf16*)(base + 48*MB);        // overwrites Khm/Vhm after attn
    float* x2_f  = xn_f;
    char* p = base + 112*MB;
    bf16*  kvw_b  = (bf16*)p;  p += (size_t)1024*DIM*2;        // in_w rows [512,1536) bf16
    bf16*  w1_b   = (bf16*)p;  p += (size_t)FFD*DIM*2;
    bf16*  w2_b   = (bf16*)p;  p += (size_t)DIM*FFD*2;
    double* xbpart= (double*)p; p += (size_t)BATCH*32*DIM*8;
    double* xbar_d= (double*)p; p += (size_t)BATCH*DIM*8;
    float* xbar_f = (float*)p;  p += (size_t)BATCH*DIM*4;
    double* diag  = (double*)p; p += (size_t)MROWS*8;
    double* spars = (double*)p; p += (size_t)MROWS*8;
    int*   topidx = (int*)p;    p += (size_t)BATCH*64*4;
    int*   selmap = (int*)p;    p += (size_t)MROWS*4;
    float* qrows  = (float*)p;  p += (size_t)BATCH*TOPQ*DIM*4;
    float* ctxb   = (float*)p;  p += (size_t)BATCH*TOPQ*DIM*4;
    float* sout   = (float*)p;  p += (size_t)BATCH*TOPQ*DIM*4;
    float* apart  = (float*)p;  p += (size_t)BATCH*NH*TOPQ*NKC*PSTR*4;  // 10.5 MB

    init_kernel<<<64, 256, 0, stream>>>(selmap);
    cvt_kernel<<<512,  256, 0, stream>>>(in_w + (size_t)DIM*DIM, kvw_b, 1024*DIM);
    cvt_kernel<<<1024, 256, 0, stream>>>(w1, w1_b, FFD*DIM);
    cvt_kernel<<<1024, 256, 0, stream>>>(w2, w2_b, DIM*FFD);
    ln1_kernel<<<MROWS, 256, 0, stream>>>(x, ln1_g, ln1_b, xn_f, xn_b, diag);
    xbar_part_kernel<<<dim3(32, BATCH), 512, 0, stream>>>(xn_f, xbpart);
    xbar_fin_kernel<<<BATCH, 512, 0, stream>>>(xbpart, xbar_d, xbar_f);
    sparsity_kernel<<<MROWS/4, 256, 0, stream>>>(xn_f, xbar_d, diag, spars);
    topk_kernel<<<BATCH, 256, 0, stream>>>(spars, topidx, selmap, out);
    // KV projection (N=1024 -> head-major K/V): grid 8x128 -> 1024 blocks, lgGX=3
    gemm128_kernel<3, bf16><<<1024, 256, 0, stream>>>(
        xn_b, kvw_b, in_b + DIM, Khm, nullptr, Vhm, DIM, 0, 3);
    qproj_kernel<<<dim3(TOPQ, BATCH), 256, 0, stream>>>(xn_f, in_w, in_b, topidx, qrows);
    attn_part_kernel<<<dim3(NKC, NH, BATCH), 256, 0, stream>>>(qrows, Khm, Vhm, apart);
    attn_reduce_kernel<<<dim3((TOPQ + 3)/4, NH, BATCH), 256, 0, stream>>>(apart, ctxb);
    outproj_kernel<<<dim3(TOPQ, BATCH), 256, 0, stream>>>(ctxb, out_w, out_b, sout);
    res_ln2_kernel<<<MROWS, 256, 0, stream>>>(x, xbar_f, sout, selmap, ln2_g, ln2_b, x2_f, h_b);
    // FFN1: grid 16x128 -> 2048 blocks, lgGX=4
    gemm128_kernel<1, bf16><<<2048, 256, 0, stream>>>(
        h_b, w1_b, b1, h1_b, nullptr, nullptr, DIM, FFD, 4);
    // FFN2: grid 4x128 -> 512 blocks, lgGX=2
    gemm128_kernel<2, float><<<512, 256, 0, stream>>>(
        h1_b, w2_b, b2, out, x2_f, nullptr, FFD, DIM, 2);
}